// Round 2
// baseline (4331.336 us; speedup 1.0000x reference)
//
#include <hip/hip_runtime.h>
#include <hip/hip_bf16.h>

// LSTMClassifier: B=64, T=2000, F=98, H=128, 2 bidirectional layers, FC 256->128->2
// Round-2 structure: chunked xg pipeline to keep peak workspace ~132 MB
// (round-1 used 361 MB and died with a GPU memory fault -> suspected ws overflow).
//  - per chunk (Tc=250): 2 MFMA GEMMs (fwd t-range cols[0:512), bwd t-range cols[512:1024))
//    into 16 MB bf16 buffers, then one recurrence launch advancing both directions
//    250 steps, carrying (h,c) in small ws state buffers.
//  - recurrence: one WG per (batch, dir), 512 threads; W_hh row in VGPRs (128),
//    h broadcast via LDS; fp32 recurrent path.

#define TT 2000
#define TC 250
#define NCH (TT / TC)
#define BB 64
#define FF 98
#define HH 128
#define G4 512      // 4*H

typedef __attribute__((ext_vector_type(8))) short short8;
typedef __attribute__((ext_vector_type(4))) float f32x4;

// ---------- x [B,1,T,F] f32 -> X0 [T*B][128] bf16 (K padded 98->128) ----------
__global__ void conv_x_kernel(const float* __restrict__ x, __hip_bfloat16* __restrict__ X0) {
    int b = blockIdx.y;
    int t0 = blockIdx.x * 16;
    int tid = threadIdx.x;
    #pragma unroll
    for (int i = 0; i < 8; ++i) {
        int e = tid + i * 256;      // 0..2047 (16 rows x 128 cols)
        int r = e >> 7;
        int f = e & 127;
        float v = (f < FF) ? x[(size_t)b * TT * FF + (size_t)(t0 + r) * FF + f] : 0.f;
        X0[((size_t)(t0 + r) * BB + b) * 128 + f] = __float2bfloat16(v);
    }
}

// ---------- W_ih pair -> bf16 [1024][Kpad], bias = b_ih + b_hh ----------
__global__ void conv_w_kernel(const float* __restrict__ wf, const float* __restrict__ wb,
                              const float* __restrict__ bihf, const float* __restrict__ bhhf,
                              const float* __restrict__ bihb, const float* __restrict__ bhhb,
                              __hip_bfloat16* __restrict__ W, float* __restrict__ bias,
                              int Kin, int Kpad) {
    int j = blockIdx.x;            // 0..1023 ; rows 0-511 fwd, 512-1023 bwd
    int dir = j >> 9;
    int jj = j & 511;
    const float* w = dir ? wb : wf;
    for (int k = threadIdx.x; k < Kpad; k += blockDim.x)
        W[(size_t)j * Kpad + k] = __float2bfloat16(k < Kin ? w[(size_t)jj * Kin + k] : 0.f);
    if (threadIdx.x == 0)
        bias[j] = dir ? (bihb[jj] + bhhb[jj]) : (bihf[jj] + bhhf[jj]);
}

// ---------- chunk GEMM: out[lr][512] = A[Aoff+lr][K] * W[c0+col][K]^T + bias ----------
// 256 thr (4 waves), tile 64 rows x 256 cols. No LDS: K tiny, W L2-resident.
template<int K>
__launch_bounds__(256, 2)
__global__ void gemm_xg_kernel(const short* __restrict__ A,
                               const short* __restrict__ W,
                               const float* __restrict__ bias,
                               __hip_bfloat16* __restrict__ out,
                               int Aoff, int c0) {
    constexpr int KS = K / 32;
    int tid = threadIdx.x;
    int l = tid & 63;
    int wv = tid >> 6;
    int r_loc = blockIdx.x * 64;               // local row base (0..15999)
    int c_loc = blockIdx.y * 256 + wv * 64;    // local col base (0..511)
    int lr = l & 15;            // row (A) / col (W) within 16-tile
    int lk = (l >> 4) * 8;      // k sub-offset

    f32x4 acc[4][4];
    #pragma unroll
    for (int a = 0; a < 4; ++a)
        #pragma unroll
        for (int b = 0; b < 4; ++b)
            acc[a][b] = (f32x4){0.f, 0.f, 0.f, 0.f};

    #pragma unroll
    for (int ks = 0; ks < KS; ++ks) {
        short8 af[4], bf[4];
        #pragma unroll
        for (int rt = 0; rt < 4; ++rt)
            af[rt] = *(const short8*)(A + (size_t)(Aoff + r_loc + rt * 16 + lr) * K + ks * 32 + lk);
        #pragma unroll
        for (int ct = 0; ct < 4; ++ct)
            bf[ct] = *(const short8*)(W + (size_t)(c0 + c_loc + ct * 16 + lr) * K + ks * 32 + lk);
        #pragma unroll
        for (int rt = 0; rt < 4; ++rt)
            #pragma unroll
            for (int ct = 0; ct < 4; ++ct)
                acc[rt][ct] = __builtin_amdgcn_mfma_f32_16x16x32_bf16(af[rt], bf[ct], acc[rt][ct], 0, 0, 0);
    }

    #pragma unroll
    for (int ct = 0; ct < 4; ++ct) {
        int col = c_loc + ct * 16 + lr;        // local col 0..511
        float bv = bias[c0 + col];
        #pragma unroll
        for (int rt = 0; rt < 4; ++rt) {
            #pragma unroll
            for (int e = 0; e < 4; ++e) {
                int row = r_loc + rt * 16 + (l >> 4) * 4 + e;   // m89-verified C layout
                out[(size_t)row * 512 + col] = __float2bfloat16(acc[rt][ct][e] + bv);
            }
        }
    }
}

// ---------- recurrence chunk: WG per (batch, dir); thread j owns gate-row j ----------
// xgF/xgB: [TC][B][512] bf16 (bwd buffer stored ascending-t; consumed descending).
__launch_bounds__(512, 2)
__global__ void rec_kernel(const __hip_bfloat16* __restrict__ xgF,
                           const __hip_bfloat16* __restrict__ xgB,
                           const float* __restrict__ whh_f,        // [512][128]
                           const float* __restrict__ whh_b,
                           __hip_bfloat16* __restrict__ yout,      // [T][B][256] (layer0) or unused
                           float* __restrict__ hstate,             // [2][64][128]
                           float* __restrict__ cstate,
                           int t0f, int writeY, int first) {
    int b = blockIdx.x;
    int dir = blockIdx.y;
    int j = threadIdx.x;
    const float* whh = dir ? whh_b : whh_f;
    const __hip_bfloat16* xg = dir ? xgB : xgF;

    // W_hh row j -> 128 VGPRs (statically indexed via full unroll)
    float4 w4[32];
    const float4* wr = (const float4*)(whh + (size_t)j * HH);
    #pragma unroll
    for (int q = 0; q < 32; ++q) w4[q] = wr[q];

    __shared__ __align__(16) float h_lds[HH];
    __shared__ float g_lds[G4];

    int sidx = (dir * BB + b) * HH;
    float c = 0.f;
    if (j < HH) {
        h_lds[j] = first ? 0.f : hstate[sidx + j];
        if (!first) c = cstate[sidx + j];
    }
    __syncthreads();

    // walk chunk buffer: fwd ascending, bwd descending
    const int stride = dir ? -(BB * 512) : (BB * 512);
    const __hip_bfloat16* p = xg + (size_t)(dir ? (TC - 1) * BB * 512 : 0) + b * 512 + j;

    float xg_cur = __bfloat162float(*p);
    __hip_bfloat16 xg_nxt = __float2bfloat16(0.f);

    for (int il = 0; il < TC; ++il) {
        if (il + 1 < TC)                 // prefetch next step (hidden under the dot)
            xg_nxt = p[stride];

        // pre = xg + dot(h, w_row)  (4 independent FMA chains; LDS same-addr broadcast)
        const float4* h4 = (const float4*)h_lds;
        float a0 = xg_cur, a1 = 0.f, a2 = 0.f, a3 = 0.f;
        #pragma unroll
        for (int q = 0; q < 32; ++q) {
            float4 hv = h4[q];
            a0 = fmaf(hv.x, w4[q].x, a0);
            a1 = fmaf(hv.y, w4[q].y, a1);
            a2 = fmaf(hv.z, w4[q].z, a2);
            a3 = fmaf(hv.w, w4[q].w, a3);
        }
        float pre = (a0 + a1) + (a2 + a3);

        // i,f,o -> sigmoid ; g (rows 256..383) -> tanh (overflow-safe)
        float gate;
        if ((j >> 7) == 2) {
            float ax = fabsf(pre);
            float e = __expf(-2.f * ax);
            float tv = (1.f - e) / (1.f + e);
            gate = pre < 0.f ? -tv : tv;
        } else {
            gate = 1.f / (1.f + __expf(-pre));
        }
        g_lds[j] = gate;
        __syncthreads();

        if (j < HH) {
            float gi = g_lds[j];
            float gf = g_lds[j + HH];
            float gg = g_lds[j + 2 * HH];
            float go = g_lds[j + 3 * HH];
            c = fmaf(gf, c, gi * gg);
            float ax = fabsf(c);
            float e = __expf(-2.f * ax);
            float tc = (1.f - e) / (1.f + e);
            tc = c < 0.f ? -tc : tc;
            float h = go * tc;
            h_lds[j] = h;
            if (writeY) {
                int t = dir ? (TT - 1 - (t0f + il)) : (t0f + il);
                yout[((size_t)t * BB + b) * 256 + dir * HH + j] = __float2bfloat16(h);
            }
        }
        __syncthreads();
        xg_cur = __bfloat162float(xg_nxt);
        p += stride;
    }

    if (j < HH) {                        // persist chunk-final state
        hstate[sidx + j] = h_lds[j];
        cstate[sidx + j] = c;
    }
}

// ---------- head: out[b] = clf( fc( [h_f, h_b] ) ) ----------
__global__ void fc_kernel(const float* __restrict__ hstate,   // [2][64][128]
                          const float* __restrict__ fcw, const float* __restrict__ fcb,
                          const float* __restrict__ clw, const float* __restrict__ clb,
                          float* __restrict__ out) {
    int b = blockIdx.x;
    int j = threadIdx.x;    // 0..127
    __shared__ float hrow[256];
    __shared__ float feat[128];
    hrow[j]       = hstate[(size_t)b * HH + j];                 // dir 0
    hrow[j + 128] = hstate[(size_t)(BB + b) * HH + j];          // dir 1
    __syncthreads();
    float acc = fcb[j];
    #pragma unroll 4
    for (int k = 0; k < 256; ++k) acc = fmaf(hrow[k], fcw[(size_t)j * 256 + k], acc);
    feat[j] = acc;
    __syncthreads();
    if (j < 2) {
        float o = clb[j];
        #pragma unroll 4
        for (int k = 0; k < 128; ++k) o = fmaf(feat[k], clw[(size_t)j * 128 + k], o);
        out[b * 2 + j] = o;
    }
}

extern "C" void kernel_launch(void* const* d_in, const int* in_sizes, int n_in,
                              void* d_out, int out_size, void* d_ws, size_t ws_size,
                              hipStream_t stream) {
    const float* x        = (const float*)d_in[0];
    const float* w_ih_l0f = (const float*)d_in[1];
    const float* w_hh_l0f = (const float*)d_in[2];
    const float* b_ih_l0f = (const float*)d_in[3];
    const float* b_hh_l0f = (const float*)d_in[4];
    const float* w_ih_l0b = (const float*)d_in[5];
    const float* w_hh_l0b = (const float*)d_in[6];
    const float* b_ih_l0b = (const float*)d_in[7];
    const float* b_hh_l0b = (const float*)d_in[8];
    const float* w_ih_l1f = (const float*)d_in[9];
    const float* w_hh_l1f = (const float*)d_in[10];
    const float* b_ih_l1f = (const float*)d_in[11];
    const float* b_hh_l1f = (const float*)d_in[12];
    const float* w_ih_l1b = (const float*)d_in[13];
    const float* w_hh_l1b = (const float*)d_in[14];
    const float* b_ih_l1b = (const float*)d_in[15];
    const float* b_hh_l1b = (const float*)d_in[16];
    const float* fc_w     = (const float*)d_in[17];
    const float* fc_b     = (const float*)d_in[18];
    const float* clf_w    = (const float*)d_in[19];
    const float* clf_b    = (const float*)d_in[20];

    char* ws = (char*)d_ws;
    size_t off = 0;
    __hip_bfloat16* X0   = (__hip_bfloat16*)(ws + off); off += (size_t)TT * BB * 128 * 2;  // 32,768,000
    __hip_bfloat16* y0   = (__hip_bfloat16*)(ws + off); off += (size_t)TT * BB * 256 * 2;  // 65,536,000
    __hip_bfloat16* bufF = (__hip_bfloat16*)(ws + off); off += (size_t)TC * BB * 512 * 2;  // 16,384,000
    __hip_bfloat16* bufB = (__hip_bfloat16*)(ws + off); off += (size_t)TC * BB * 512 * 2;  // 16,384,000
    __hip_bfloat16* W0   = (__hip_bfloat16*)(ws + off); off += (size_t)1024 * 128 * 2;
    __hip_bfloat16* W1   = (__hip_bfloat16*)(ws + off); off += (size_t)1024 * 256 * 2;
    float* bias0  = (float*)(ws + off); off += 1024 * 4;
    float* bias1  = (float*)(ws + off); off += 1024 * 4;
    float* hstate = (float*)(ws + off); off += 2 * BB * HH * 4;
    float* cstate = (float*)(ws + off); off += 2 * BB * HH * 4;
    // peak ws ~132 MB

    conv_x_kernel<<<dim3(TT / 16, BB), 256, 0, stream>>>(x, X0);
    conv_w_kernel<<<1024, 128, 0, stream>>>(w_ih_l0f, w_ih_l0b, b_ih_l0f, b_hh_l0f,
                                            b_ih_l0b, b_hh_l0b, W0, bias0, 98, 128);
    conv_w_kernel<<<1024, 256, 0, stream>>>(w_ih_l1f, w_ih_l1b, b_ih_l1f, b_hh_l1f,
                                            b_ih_l1b, b_hh_l1b, W1, bias1, 256, 256);

    dim3 ggrid(TC * BB / 64, 2);

    // layer 0
    for (int k = 0; k < NCH; ++k) {
        gemm_xg_kernel<128><<<ggrid, 256, 0, stream>>>(
            (const short*)X0, (const short*)W0, bias0, bufF, k * TC * BB, 0);
        gemm_xg_kernel<128><<<ggrid, 256, 0, stream>>>(
            (const short*)X0, (const short*)W0, bias0, bufB, (TT - (k + 1) * TC) * BB, 512);
        rec_kernel<<<dim3(BB, 2), 512, 0, stream>>>(
            bufF, bufB, w_hh_l0f, w_hh_l0b, y0, hstate, cstate, k * TC, 1, k == 0);
    }

    // layer 1 (only final h needed by the head)
    for (int k = 0; k < NCH; ++k) {
        gemm_xg_kernel<256><<<ggrid, 256, 0, stream>>>(
            (const short*)y0, (const short*)W1, bias1, bufF, k * TC * BB, 0);
        gemm_xg_kernel<256><<<ggrid, 256, 0, stream>>>(
            (const short*)y0, (const short*)W1, bias1, bufB, (TT - (k + 1) * TC) * BB, 512);
        rec_kernel<<<dim3(BB, 2), 512, 0, stream>>>(
            bufF, bufB, w_hh_l1f, w_hh_l1b, y0 /*unused*/, hstate, cstate, k * TC, 0, k == 0);
    }

    fc_kernel<<<BB, 128, 0, stream>>>(hstate, fc_w, fc_b, clf_w, clf_b, (float*)d_out);
}